// Round 1
// baseline (7326.210 us; speedup 1.0000x reference)
//
#include <hip/hip_runtime.h>
#include <stdint.h>

#define V_  32000
#define E_  1024
#define H_  1024
#define B_  64
#define T_  128
#define NC_ 500   // vocab chunks of 64

typedef __bf16 bf16x8 __attribute__((ext_vector_type(8)));
typedef float  f32x4  __attribute__((ext_vector_type(4)));

__device__ __forceinline__ uint16_t f2b(float f) {
  uint32_t u = __builtin_bit_cast(uint32_t, f);
  return (uint16_t)((u + 0x7fffu + ((u >> 16) & 1u)) >> 16);
}
__device__ __forceinline__ float b2f(uint16_t h) {
  uint32_t u = ((uint32_t)h) << 16;
  return __builtin_bit_cast(float, u);
}
__device__ __forceinline__ float sigmoidf_(float x) { return 1.0f / (1.0f + expf(-x)); }

// ---------------- setup kernels ----------------

__global__ void k_cvt(const float* __restrict__ src, uint16_t* __restrict__ dst, int n4) {
  int i = blockIdx.x * blockDim.x + threadIdx.x;
  int st = gridDim.x * blockDim.x;
  for (; i < n4; i += st) {
    float4 v = ((const float4*)src)[i];
    ushort4 o;
    o.x = f2b(v.x); o.y = f2b(v.y); o.z = f2b(v.z); o.w = f2b(v.w);
    ((ushort4*)dst)[i] = o;
  }
}

// src (R x C) f32 -> dst (C x R) bf16
__global__ void k_tcvt(const float* __restrict__ src, uint16_t* __restrict__ dst, int R, int C) {
  __shared__ float tile[32][33];
  int c0 = blockIdx.x * 32, r0 = blockIdx.y * 32;
  int tx = threadIdx.x, ty = threadIdx.y;  // (32,8)
  for (int j = 0; j < 32; j += 8)
    tile[ty + j][tx] = src[(size_t)(r0 + ty + j) * C + c0 + tx];
  __syncthreads();
  for (int j = 0; j < 32; j += 8)
    dst[(size_t)(c0 + ty + j) * R + r0 + tx] = f2b(tile[tx][ty + j]);
}

__global__ void k_zero(uint4* p, int n) {
  int i = blockIdx.x * blockDim.x + threadIdx.x;
  int st = gridDim.x * blockDim.x;
  uint4 z = {0, 0, 0, 0};
  for (; i < n; i += st) p[i] = z;
}

// ---------------- recurrence ----------------
// g[b][j] = sum_k emb[tok[b]][k] * W_ih[k][j] + sum_k h[b][k] * W_hh[k][j]
// grid: 256 blocks (j-chunks of 16), 256 threads (4 waves; wave w covers b rows 16w..16w+15)
__global__ __launch_bounds__(256) void k_gates(
    const int* __restrict__ data, const uint16_t* __restrict__ embB,
    const uint16_t* __restrict__ WihT, const uint16_t* __restrict__ WhhT,
    const uint16_t* __restrict__ hIn, float* __restrict__ g, int t)
{
  __shared__ int tok[B_];
  int tid = threadIdx.x;
  if (tid < B_) tok[tid] = data[t * B_ + tid];
  __syncthreads();
  int w = tid >> 6, l = tid & 63, lr = l & 15, lg = l >> 4;
  int j0 = blockIdx.x * 16;
  int b  = 16 * w + lr;
  const uint16_t* embRow = embB + (size_t)tok[b] * E_ + lg * 8;
  const uint16_t* hRow   = hIn  + (size_t)b * H_ + lg * 8;
  const uint16_t* wih    = WihT + (size_t)(j0 + lr) * E_ + lg * 8;
  const uint16_t* whh    = WhhT + (size_t)(j0 + lr) * H_ + lg * 8;
  f32x4 acc = {0.f, 0.f, 0.f, 0.f};
#pragma unroll 4
  for (int ks = 0; ks < 32; ++ks) {   // x @ W_ih
    bf16x8 a  = *(const bf16x8*)(embRow + ks * 32);
    bf16x8 bb = *(const bf16x8*)(wih + ks * 32);
    acc = __builtin_amdgcn_mfma_f32_16x16x32_bf16(a, bb, acc, 0, 0, 0);
  }
#pragma unroll 4
  for (int ks = 0; ks < 32; ++ks) {   // h @ W_hh
    bf16x8 a  = *(const bf16x8*)(hRow + ks * 32);
    bf16x8 bb = *(const bf16x8*)(whh + ks * 32);
    acc = __builtin_amdgcn_mfma_f32_16x16x32_bf16(a, bb, acc, 0, 0, 0);
  }
  int bb_ = 16 * w + lg * 4;
#pragma unroll
  for (int r = 0; r < 4; ++r)
    g[(size_t)(bb_ + r) * (4 * H_) + j0 + lr] = acc[r];
}

__global__ __launch_bounds__(256) void k_lstm(
    const float* __restrict__ g, const float* __restrict__ bias,
    const float* __restrict__ mask, const uint16_t* __restrict__ hIn,
    uint16_t* __restrict__ hOut, float* __restrict__ c, int t)
{
  int idx = blockIdx.x * 256 + threadIdx.x;   // 0..65535
  int b = idx >> 10, u = idx & 1023;
  size_t gb = (size_t)b * (4 * H_);
  float iv = sigmoidf_(g[gb + u]            + bias[u]);
  float fv = sigmoidf_(g[gb + 1024 + u]     + bias[1024 + u]);
  float gv = tanhf    (g[gb + 2048 + u]     + bias[2048 + u]);
  float ov = sigmoidf_(g[gb + 3072 + u]     + bias[3072 + u]);
  float co = c[idx];
  float ho = b2f(hIn[idx]);
  float cn = fv * co + iv * gv;
  float hn = ov * tanhf(cn);
  float mm = mask[(t + 1) * B_ + b];
  float c2 = mm * cn + (1.f - mm) * co;
  float h2 = mm * hn + (1.f - mm) * ho;
  c[idx] = c2;
  hOut[idx] = f2b(h2);
}

// ---------------- batched projection: out[t*B+b][e] = h[t+1][b] . Wr[e] + br[e] ----------------
// grid: (E/64, T), 256 threads
__global__ __launch_bounds__(256) void k_out(
    const uint16_t* __restrict__ hAll, const uint16_t* __restrict__ WrB,
    const float* __restrict__ br, uint16_t* __restrict__ outAll)
{
  int tid = threadIdx.x, w = tid >> 6, l = tid & 63, lr = l & 15, lg = l >> 4;
  int t = blockIdx.y;
  int e0 = blockIdx.x * 64;
  const uint16_t* aRow = hAll + ((size_t)(t + 1) * B_ + 16 * w + lr) * H_ + lg * 8;
  f32x4 acc[4] = {};
#pragma unroll 2
  for (int ks = 0; ks < 32; ++ks) {
    bf16x8 a = *(const bf16x8*)(aRow + ks * 32);
#pragma unroll
    for (int n = 0; n < 4; ++n) {
      bf16x8 bb = *(const bf16x8*)(WrB + (size_t)(e0 + n * 16 + lr) * H_ + lg * 8 + ks * 32);
      acc[n] = __builtin_amdgcn_mfma_f32_16x16x32_bf16(a, bb, acc[n], 0, 0, 0);
    }
  }
  int bb_ = 16 * w + lg * 4;
#pragma unroll
  for (int n = 0; n < 4; ++n) {
    int e = e0 + n * 16 + lr;
    float brv = br[e];
#pragma unroll
    for (int r = 0; r < 4; ++r)
      outAll[((size_t)t * B_ + bb_ + r) * E_ + e] = f2b(acc[n][r] + brv);
  }
}

// ---------------- batched logits + per-chunk softmax partials ----------------
// grid: (NC, T), 256 threads. Chunk = 64 vocab rows.
__global__ __launch_bounds__(256) void k_logits(
    const uint16_t* __restrict__ outAll, const uint16_t* __restrict__ embB,
    const float* __restrict__ bd, const int* __restrict__ data,
    float2* __restrict__ part, float* __restrict__ tgt)
{
  int tid = threadIdx.x, w = tid >> 6, l = tid & 63, lr = l & 15, lg = l >> 4;
  int t = blockIdx.y;
  int vb = blockIdx.x * 64;
  const uint16_t* aRow = outAll + ((size_t)t * B_ + 16 * w + lr) * E_ + lg * 8;
  f32x4 acc[4] = {};
#pragma unroll 2
  for (int ks = 0; ks < 32; ++ks) {
    bf16x8 a = *(const bf16x8*)(aRow + ks * 32);
#pragma unroll
    for (int n = 0; n < 4; ++n) {
      bf16x8 bb = *(const bf16x8*)(embB + (size_t)(vb + n * 16 + lr) * E_ + lg * 8 + ks * 32);
      acc[n] = __builtin_amdgcn_mfma_f32_16x16x32_bf16(a, bb, acc[n], 0, 0, 0);
    }
  }
  // add bd[v]  (C layout: col v = vb + n*16 + (l&15); row b = 16w + (l>>4)*4 + r)
#pragma unroll
  for (int n = 0; n < 4; ++n) {
    float bdv = bd[vb + n * 16 + lr];
#pragma unroll
    for (int r = 0; r < 4; ++r) acc[n][r] += bdv;
  }
  // target logit
#pragma unroll
  for (int r = 0; r < 4; ++r) {
    int b = 16 * w + lg * 4 + r;
    int ty = data[(size_t)(t + 1) * B_ + b];
    int col = ty - vb;
    if (col >= 0 && col < 64 && (col & 15) == lr) {
#pragma unroll
      for (int n = 0; n < 4; ++n)
        if ((col >> 4) == n) tgt[t * B_ + b] = acc[n][r];
    }
  }
  // per-b chunk max + sum-exp (reduce over 16 lanes of each row-group)
  float pm[4], ps[4];
#pragma unroll
  for (int r = 0; r < 4; ++r) {
    float m = fmaxf(fmaxf(acc[0][r], acc[1][r]), fmaxf(acc[2][r], acc[3][r]));
#pragma unroll
    for (int d = 1; d < 16; d <<= 1) m = fmaxf(m, __shfl_xor(m, d, 64));
    float s = 0.f;
#pragma unroll
    for (int n = 0; n < 4; ++n) s += expf(acc[n][r] - m);
#pragma unroll
    for (int d = 1; d < 16; d <<= 1) s += __shfl_xor(s, d, 64);
    pm[r] = m; ps[r] = s;
  }
  size_t base = ((size_t)t * NC_ + blockIdx.x) * B_;
#pragma unroll
  for (int r = 0; r < 4; ++r)
    if (lr == r) part[base + 16 * w + lg * 4 + r] = make_float2(pm[r], ps[r]);
}

// ---------------- reductions ----------------
__global__ __launch_bounds__(256) void k_reduce(
    const float2* __restrict__ part, const float* __restrict__ tgt,
    const float* __restrict__ mask, float* __restrict__ stepLoss)
{
  int t = blockIdx.x;
  int tid = threadIdx.x;
  int b = tid >> 2, q = tid & 3;
  const float2* p = part + (size_t)t * NC_ * B_ + b;
  float mm = -1e30f;
  for (int cc = q; cc < NC_; cc += 4) mm = fmaxf(mm, p[(size_t)cc * B_].x);
  mm = fmaxf(mm, __shfl_xor(mm, 1, 64));
  mm = fmaxf(mm, __shfl_xor(mm, 2, 64));
  float ss = 0.f;
  for (int cc = q; cc < NC_; cc += 4) {
    float2 v = p[(size_t)cc * B_];
    ss += v.y * expf(v.x - mm);
  }
  ss += __shfl_xor(ss, 1, 64);
  ss += __shfl_xor(ss, 2, 64);
  float lse = mm + logf(ss);
  float nll = lse - tgt[t * B_ + b];
  float contrib = nll * mask[(t + 1) * B_ + b];
  __shared__ float red[B_];
  if (q == 0) red[b] = contrib;
  __syncthreads();
  for (int st = 32; st > 0; st >>= 1) {
    if (tid < st) red[tid] += red[tid + st];
    __syncthreads();
  }
  if (tid == 0) stepLoss[t] = red[0];
}

__global__ void k_final(const float* __restrict__ stepLoss, float* __restrict__ out) {
  __shared__ float red[T_];
  red[threadIdx.x] = stepLoss[threadIdx.x];
  __syncthreads();
  for (int st = T_ / 2; st > 0; st >>= 1) {
    if ((int)threadIdx.x < st) red[threadIdx.x] += red[threadIdx.x + st];
    __syncthreads();
  }
  if (threadIdx.x == 0) out[0] = red[0] / (float)(B_ * B_);
}

// ---------------- host ----------------
extern "C" void kernel_launch(void* const* d_in, const int* in_sizes, int n_in,
                              void* d_out, int out_size, void* d_ws, size_t ws_size,
                              hipStream_t stream)
{
  const int*   data = (const int*)  d_in[0];
  const float* mask = (const float*)d_in[1];
  const float* emb  = (const float*)d_in[2];
  const float* W_ih = (const float*)d_in[3];
  const float* W_hh = (const float*)d_in[4];
  const float* bias = (const float*)d_in[5];
  const float* Wr   = (const float*)d_in[6];
  const float* br   = (const float*)d_in[7];
  const float* bd   = (const float*)d_in[8];
  (void)in_sizes; (void)n_in; (void)out_size; (void)ws_size;

  char* ws = (char*)d_ws;
  size_t off = 0;
  auto alloc = [&](size_t bytes) -> char* {
    char* p = ws + off;
    off += (bytes + 255) & ~(size_t)255;
    return p;
  };
  uint16_t* embB   = (uint16_t*)alloc((size_t)V_ * E_ * 2);        // 65.5 MB
  uint16_t* WihT   = (uint16_t*)alloc((size_t)4 * H_ * E_ * 2);    // 8.4 MB
  uint16_t* WhhT   = (uint16_t*)alloc((size_t)4 * H_ * H_ * 2);    // 8.4 MB
  uint16_t* WrB    = (uint16_t*)alloc((size_t)E_ * H_ * 2);        // 2.1 MB
  uint16_t* hAll   = (uint16_t*)alloc((size_t)(T_ + 1) * B_ * H_ * 2); // 16.9 MB
  float*    c      = (float*)   alloc((size_t)B_ * H_ * 4);
  float*    g      = (float*)   alloc((size_t)B_ * 4 * H_ * 4);
  uint16_t* outAll = (uint16_t*)alloc((size_t)T_ * B_ * E_ * 2);   // 16.8 MB
  float2*   part   = (float2*)  alloc((size_t)T_ * NC_ * B_ * 8);  // 32.8 MB
  float*    tgt    = (float*)   alloc((size_t)T_ * B_ * 4);
  float*    stepLoss = (float*) alloc((size_t)T_ * 4);

  // one-time conversions
  k_cvt <<<2048, 256, 0, stream>>>(emb, embB, V_ * E_ / 4);
  k_cvt <<<256,  256, 0, stream>>>(Wr, WrB, E_ * H_ / 4);
  k_tcvt<<<dim3(4 * H_ / 32, E_ / 32), dim3(32, 8), 0, stream>>>(W_ih, WihT, E_, 4 * H_);
  k_tcvt<<<dim3(4 * H_ / 32, H_ / 32), dim3(32, 8), 0, stream>>>(W_hh, WhhT, H_, 4 * H_);
  k_zero<<<32, 256, 0, stream>>>((uint4*)hAll, B_ * H_ * 2 / 16);
  k_zero<<<64, 256, 0, stream>>>((uint4*)c,    B_ * H_ * 4 / 16);

  // sequential recurrence (stores every h_t)
  for (int t = 0; t < T_; ++t) {
    k_gates<<<256, 256, 0, stream>>>(data, embB, WihT, WhhT,
                                     hAll + (size_t)t * B_ * H_, g, t);
    k_lstm <<<256, 256, 0, stream>>>(g, bias, mask,
                                     hAll + (size_t)t * B_ * H_,
                                     hAll + (size_t)(t + 1) * B_ * H_, c, t);
  }

  // batched projection + batched vocab logits/softmax partials
  k_out   <<<dim3(E_ / 64, T_), 256, 0, stream>>>(hAll, WrB, br, outAll);
  k_logits<<<dim3(NC_, T_),     256, 0, stream>>>(outAll, embB, bd, data, part, tgt);

  k_reduce<<<T_, 256, 0, stream>>>(part, tgt, mask, stepLoss);
  k_final <<<1, T_, 0, stream>>>(stepLoss, (float*)d_out);
}

// Round 2
// 3368.543 us; speedup vs baseline: 2.1749x; 2.1749x over previous
//
#include <hip/hip_runtime.h>
#include <stdint.h>

#define V_  32000
#define E_  1024
#define H_  1024
#define B_  64
#define T_  128
#define MROWS (T_ * B_)      // 8192
#define NCB 250              // 32000 / 128 vocab chunks

typedef __bf16 bf16x8 __attribute__((ext_vector_type(8)));
typedef float  f32x4  __attribute__((ext_vector_type(4)));

__device__ __forceinline__ uint16_t f2b(float f) {
  uint32_t u = __builtin_bit_cast(uint32_t, f);
  return (uint16_t)((u + 0x7fffu + ((u >> 16) & 1u)) >> 16);
}
__device__ __forceinline__ float b2f(uint16_t h) {
  uint32_t u = ((uint32_t)h) << 16;
  return __builtin_bit_cast(float, u);
}
__device__ __forceinline__ float sigmoidf_(float x) { return 1.0f / (1.0f + expf(-x)); }

__device__ __forceinline__ void gload16(const uint16_t* g, uint16_t* l) {
  __builtin_amdgcn_global_load_lds(
      (const __attribute__((address_space(1))) uint32_t*)g,
      (__attribute__((address_space(3))) uint32_t*)l,
      16, 0, 0);
}

// ---------------- setup kernels ----------------

__global__ void k_cvt(const float* __restrict__ src, uint16_t* __restrict__ dst, int n4) {
  int i = blockIdx.x * blockDim.x + threadIdx.x;
  int st = gridDim.x * blockDim.x;
  for (; i < n4; i += st) {
    float4 v = ((const float4*)src)[i];
    ushort4 o;
    o.x = f2b(v.x); o.y = f2b(v.y); o.z = f2b(v.z); o.w = f2b(v.w);
    ((ushort4*)dst)[i] = o;
  }
}

// src (R x C) f32 -> dst[col * dstStride + dstOff + row] bf16 (transpose-convert)
__global__ void k_tcvt(const float* __restrict__ src, uint16_t* __restrict__ dst,
                       int R, int C, int dstStride, int dstOff) {
  __shared__ float tile[32][33];
  int c0 = blockIdx.x * 32, r0 = blockIdx.y * 32;
  int tx = threadIdx.x, ty = threadIdx.y;  // (32,8)
  for (int j = 0; j < 32; j += 8)
    tile[ty + j][tx] = src[(size_t)(r0 + ty + j) * C + c0 + tx];
  __syncthreads();
  for (int j = 0; j < 32; j += 8)
    dst[(size_t)(c0 + ty + j) * dstStride + dstOff + r0 + tx] = f2b(tile[tx][ty + j]);
}

__global__ void k_zero(uint4* p, int n) {
  int i = blockIdx.x * blockDim.x + threadIdx.x;
  int st = gridDim.x * blockDim.x;
  uint4 z = {0, 0, 0, 0};
  for (; i < n; i += st) p[i] = z;
}

// ---------------- fused recurrence step ----------------
// Block bi handles units u0=bi*4 .. u0+3, ALL 4 gates, all 64 batch rows.
// GEMM: 64(M) x 16(cols: gate q=lr>>2, unit v=lr&3) x K=2048 (emb ; h).
// Then in-block LSTM pointwise; writes hOut (bf16) + c (f32).
__global__ __launch_bounds__(256) void k_step(
    const int* __restrict__ data, const uint16_t* __restrict__ embB,
    const uint16_t* __restrict__ Wcat,   // [4096 cols][2048 k] bf16
    const float* __restrict__ bias, const float* __restrict__ mask,
    const uint16_t* __restrict__ hIn, uint16_t* __restrict__ hOut,
    float* __restrict__ c, int t)
{
  __shared__ int tokS[B_];
  __shared__ float lds_g[4][B_][4];
  int tid = threadIdx.x;
  if (tid < B_) tokS[tid] = data[t * B_ + tid];
  __syncthreads();

  int w = tid >> 6, l = tid & 63, lr = l & 15, lg = l >> 4;
  int u0 = blockIdx.x * 4;
  int brow = 16 * w + lr;

  const uint16_t* aE = embB + (size_t)tokS[brow] * E_ + lg * 8;
  const uint16_t* aH = hIn  + (size_t)brow * H_ + lg * 8;
  const uint16_t* bW = Wcat + (size_t)((lr >> 2) * 1024 + u0 + (lr & 3)) * 2048 + lg * 8;

  f32x4 acc = {0.f, 0.f, 0.f, 0.f};
#pragma unroll 8
  for (int ks = 0; ks < 32; ++ks) {
    bf16x8 a  = *(const bf16x8*)(aE + ks * 32);
    bf16x8 bb = *(const bf16x8*)(bW + ks * 32);
    acc = __builtin_amdgcn_mfma_f32_16x16x32_bf16(a, bb, acc, 0, 0, 0);
  }
#pragma unroll 8
  for (int ks = 0; ks < 32; ++ks) {
    bf16x8 a  = *(const bf16x8*)(aH + ks * 32);
    bf16x8 bb = *(const bf16x8*)(bW + 1024 + ks * 32);
    acc = __builtin_amdgcn_mfma_f32_16x16x32_bf16(a, bb, acc, 0, 0, 0);
  }
#pragma unroll
  for (int r = 0; r < 4; ++r)
    lds_g[lr >> 2][16 * w + lg * 4 + r][lr & 3] = acc[r];
  __syncthreads();

  // pointwise: thread -> (b, u)
  int b = tid >> 2, u = tid & 3;
  int uu = u0 + u;
  float gi = sigmoidf_(lds_g[0][b][u] + bias[uu]);
  float gf = sigmoidf_(lds_g[1][b][u] + bias[1024 + uu]);
  float gt = tanhf    (lds_g[2][b][u] + bias[2048 + uu]);
  float go = sigmoidf_(lds_g[3][b][u] + bias[3072 + uu]);
  int idx = b * 1024 + uu;
  float co = c[idx];
  float ho = b2f(hIn[idx]);
  float cn = gf * co + gi * gt;
  float hn = go * tanhf(cn);
  float mm = mask[(t + 1) * B_ + b];
  c[idx]    = mm * cn + (1.f - mm) * co;
  hOut[idx] = f2b(mm * hn + (1.f - mm) * ho);
}

// ---------------- batched projection: out[t*B+b][e] = h[t+1][b] . Wr[e] + br[e] ----------------
__global__ __launch_bounds__(256) void k_out(
    const uint16_t* __restrict__ hAll, const uint16_t* __restrict__ WrB,
    const float* __restrict__ br, uint16_t* __restrict__ outAll)
{
  int tid = threadIdx.x, w = tid >> 6, l = tid & 63, lr = l & 15, lg = l >> 4;
  int t = blockIdx.y;
  int e0 = blockIdx.x * 64;
  const uint16_t* aRow = hAll + ((size_t)(t + 1) * B_ + 16 * w + lr) * H_ + lg * 8;
  f32x4 acc[4] = {};
#pragma unroll 2
  for (int ks = 0; ks < 32; ++ks) {
    bf16x8 a = *(const bf16x8*)(aRow + ks * 32);
#pragma unroll
    for (int n = 0; n < 4; ++n) {
      bf16x8 bb = *(const bf16x8*)(WrB + (size_t)(e0 + n * 16 + lr) * H_ + lg * 8 + ks * 32);
      acc[n] = __builtin_amdgcn_mfma_f32_16x16x32_bf16(a, bb, acc[n], 0, 0, 0);
    }
  }
  int bb_ = 16 * w + lg * 4;
#pragma unroll
  for (int n = 0; n < 4; ++n) {
    int e = e0 + n * 16 + lr;
    float brv = br[e];
#pragma unroll
    for (int r = 0; r < 4; ++r)
      outAll[((size_t)t * B_ + bb_ + r) * E_ + e] = f2b(acc[n][r] + brv);
  }
}

// ---------------- big logits GEMM (m97 structure) + softmax partials ----------------
// C = A(8192x1024) . Bm(32000x1024)^T ; 128x128 tile, BK=64, 4 waves (2x2),
// global_load_lds w/ inverse-swizzled source, swizzled ds_read_b128.
// Epilogue: per-row {max, sumexp} over the 128-col chunk -> part[chunk][row].
__global__ __launch_bounds__(256) void k_logits2(
    const uint16_t* __restrict__ A, const uint16_t* __restrict__ Bm,
    const float* __restrict__ bd, float2* __restrict__ part)
{
  __shared__ uint16_t lA[128 * 64];
  __shared__ uint16_t lB[128 * 64];
  __shared__ float2 cm[2][128];

  int tid = threadIdx.x;
  int w = tid >> 6, l = tid & 63, lr = l & 15, lg = l >> 4;
  int wr = w >> 1, wc = w & 1;
  int m0 = blockIdx.x * 128;
  int n0 = blockIdx.y * 128;

  // staging geometry: chunk = 1KB = 8 rows x 64B; wave w stages chunks 4w..4w+3
  int stRow = l >> 3;                               // 0..7 within chunk
  int kswz  = ((l & 7) * 8) ^ ((stRow & 7) << 3);   // inverse-swizzled k source (elems)
  const uint16_t* aSrc = A  + (size_t)(m0 + w * 32 + stRow) * 1024 + kswz;
  const uint16_t* bSrc = Bm + (size_t)(n0 + w * 32 + stRow) * 1024 + kswz;

  f32x4 acc[4][4] = {};

  for (int kt = 0; kt < 1024; kt += 64) {
#pragma unroll
    for (int cc = 0; cc < 4; ++cc) {
      gload16(aSrc + (size_t)cc * 8 * 1024 + kt, &lA[(w * 4 + cc) * 512]);
      gload16(bSrc + (size_t)cc * 8 * 1024 + kt, &lB[(w * 4 + cc) * 512]);
    }
    __syncthreads();   // drains vmcnt -> staged data visible
#pragma unroll
    for (int ksub = 0; ksub < 2; ++ksub) {
      bf16x8 af[4], bf[4];
      int ke = ksub * 32 + lg * 8;
#pragma unroll
      for (int mi = 0; mi < 4; ++mi) {
        int row = wr * 64 + mi * 16 + lr;
        af[mi] = *(const bf16x8*)&lA[row * 64 + (ke ^ ((row & 7) << 3))];
      }
#pragma unroll
      for (int ni = 0; ni < 4; ++ni) {
        int row = wc * 64 + ni * 16 + lr;
        bf[ni] = *(const bf16x8*)&lB[row * 64 + (ke ^ ((row & 7) << 3))];
      }
#pragma unroll
      for (int mi = 0; mi < 4; ++mi)
#pragma unroll
        for (int ni = 0; ni < 4; ++ni)
          acc[mi][ni] = __builtin_amdgcn_mfma_f32_16x16x32_bf16(af[mi], bf[ni], acc[mi][ni], 0, 0, 0);
    }
    __syncthreads();
  }

  // epilogue: add bd, per-row {max, sumexp} over this wave's 64 cols
  float bdv[4];
#pragma unroll
  for (int ni = 0; ni < 4; ++ni) bdv[ni] = bd[n0 + wc * 64 + ni * 16 + lr];
#pragma unroll
  for (int mi = 0; mi < 4; ++mi) {
#pragma unroll
    for (int r = 0; r < 4; ++r) {
      float mx = -1e30f;
#pragma unroll
      for (int ni = 0; ni < 4; ++ni) { acc[mi][ni][r] += bdv[ni]; mx = fmaxf(mx, acc[mi][ni][r]); }
#pragma unroll
      for (int d = 1; d < 16; d <<= 1) mx = fmaxf(mx, __shfl_xor(mx, d, 64));
      float s = 0.f;
#pragma unroll
      for (int ni = 0; ni < 4; ++ni) s += expf(acc[mi][ni][r] - mx);
#pragma unroll
      for (int d = 1; d < 16; d <<= 1) s += __shfl_xor(s, d, 64);
      if (lr == 0) cm[wc][wr * 64 + mi * 16 + lg * 4 + r] = make_float2(mx, s);
    }
  }
  __syncthreads();
  if (tid < 128) {
    float2 p0 = cm[0][tid], p1 = cm[1][tid];
    float M = fmaxf(p0.x, p1.x);
    float S = p0.y * expf(p0.x - M) + p1.y * expf(p1.x - M);
    part[(size_t)blockIdx.y * MROWS + m0 + tid] = make_float2(M, S);
  }
}

// ---------------- target logits: tgt[row] = outAll[row] . embB[ty] + bd[ty] ----------------
__global__ __launch_bounds__(256) void k_tgt(
    const uint16_t* __restrict__ outAll, const uint16_t* __restrict__ embB,
    const float* __restrict__ bd, const int* __restrict__ data, float* __restrict__ tgt)
{
  int w = threadIdx.x >> 6, l = threadIdx.x & 63;
  int row = blockIdx.x * 4 + w;
  int t = row >> 6, b = row & 63;
  int ty = data[(t + 1) * B_ + b];
  const uint16_t* a = outAll + (size_t)row * E_;
  const uint16_t* e = embB + (size_t)ty * E_;
  float s = 0.f;
#pragma unroll
  for (int i0 = 0; i0 < 2; ++i0) {
    int i = (l + i0 * 64) * 8;
    bf16x8 av = *(const bf16x8*)(a + i);
    bf16x8 ev = *(const bf16x8*)(e + i);
#pragma unroll
    for (int j = 0; j < 8; ++j) s += (float)av[j] * (float)ev[j];
  }
#pragma unroll
  for (int d = 1; d < 64; d <<= 1) s += __shfl_xor(s, d, 64);
  if (l == 0) tgt[row] = s + bd[ty];
}

// ---------------- LSE over 250 chunks + NLL per row ----------------
__global__ __launch_bounds__(256) void k_lse(
    const float2* __restrict__ part, const float* __restrict__ tgt,
    const float* __restrict__ mask, float* __restrict__ rowNll)
{
  int w = threadIdx.x >> 6, l = threadIdx.x & 63;
  int row = blockIdx.x * 4 + w;
  float m = -1e30f, s = 0.f;
  for (int cc = l; cc < NCB; cc += 64) {
    float2 v = part[(size_t)cc * MROWS + row];
    float M = fmaxf(m, v.x);
    s = s * expf(m - M) + v.y * expf(v.x - M);
    m = M;
  }
#pragma unroll
  for (int d = 1; d < 64; d <<= 1) {
    float om = __shfl_xor(m, d, 64);
    float os = __shfl_xor(s, d, 64);
    float M = fmaxf(m, om);
    s = s * expf(m - M) + os * expf(om - M);
    m = M;
  }
  if (l == 0) {
    int t = row >> 6, b = row & 63;
    float nll = (m + logf(s)) - tgt[row];
    rowNll[row] = nll * mask[(t + 1) * B_ + b];
  }
}

__global__ void k_final2(const float* __restrict__ rowNll, float* __restrict__ out) {
  __shared__ float red[256];
  float s = 0.f;
  for (int i = threadIdx.x; i < MROWS; i += 256) s += rowNll[i];
  red[threadIdx.x] = s;
  __syncthreads();
  for (int st = 128; st > 0; st >>= 1) {
    if ((int)threadIdx.x < st) red[threadIdx.x] += red[threadIdx.x + st];
    __syncthreads();
  }
  if (threadIdx.x == 0) out[0] = red[0] / (float)(B_ * B_);
}

// ---------------- host ----------------
extern "C" void kernel_launch(void* const* d_in, const int* in_sizes, int n_in,
                              void* d_out, int out_size, void* d_ws, size_t ws_size,
                              hipStream_t stream)
{
  const int*   data = (const int*)  d_in[0];
  const float* mask = (const float*)d_in[1];
  const float* emb  = (const float*)d_in[2];
  const float* W_ih = (const float*)d_in[3];
  const float* W_hh = (const float*)d_in[4];
  const float* bias = (const float*)d_in[5];
  const float* Wr   = (const float*)d_in[6];
  const float* br   = (const float*)d_in[7];
  const float* bd   = (const float*)d_in[8];
  (void)in_sizes; (void)n_in; (void)out_size; (void)ws_size;

  char* ws = (char*)d_ws;
  size_t off = 0;
  auto alloc = [&](size_t bytes) -> char* {
    char* p = ws + off;
    off += (bytes + 255) & ~(size_t)255;
    return p;
  };
  uint16_t* embB   = (uint16_t*)alloc((size_t)V_ * E_ * 2);            // 65.5 MB
  uint16_t* Wcat   = (uint16_t*)alloc((size_t)4 * H_ * 2048 * 2);      // 16.8 MB
  uint16_t* WrB    = (uint16_t*)alloc((size_t)E_ * H_ * 2);            // 2.1 MB
  uint16_t* hAll   = (uint16_t*)alloc((size_t)(T_ + 1) * B_ * H_ * 2); // 16.9 MB
  float*    c      = (float*)   alloc((size_t)B_ * H_ * 4);
  uint16_t* outAll = (uint16_t*)alloc((size_t)MROWS * E_ * 2);         // 16.8 MB
  float2*   part   = (float2*)  alloc((size_t)NCB * MROWS * 8);        // 16.4 MB
  float*    tgt    = (float*)   alloc((size_t)MROWS * 4);
  float*    rowNll = (float*)   alloc((size_t)MROWS * 4);

  // one-time conversions
  k_cvt <<<2048, 256, 0, stream>>>(emb, embB, V_ * E_ / 4);
  k_cvt <<<256,  256, 0, stream>>>(Wr, WrB, E_ * H_ / 4);
  // W_ih (E x 4H) -> Wcat[col][0..1023];  W_hh (H x 4H) -> Wcat[col][1024..2047]
  k_tcvt<<<dim3(4 * H_ / 32, E_ / 32), dim3(32, 8), 0, stream>>>(W_ih, Wcat, E_, 4 * H_, 2048, 0);
  k_tcvt<<<dim3(4 * H_ / 32, H_ / 32), dim3(32, 8), 0, stream>>>(W_hh, Wcat, H_, 4 * H_, 2048, 1024);
  k_zero<<<32, 256, 0, stream>>>((uint4*)hAll, B_ * H_ * 2 / 16);
  k_zero<<<64, 256, 0, stream>>>((uint4*)c,    B_ * H_ * 4 / 16);

  // fused sequential recurrence
  for (int t = 0; t < T_; ++t) {
    k_step<<<256, 256, 0, stream>>>(data, embB, Wcat, bias, mask,
                                    hAll + (size_t)t * B_ * H_,
                                    hAll + (size_t)(t + 1) * B_ * H_, c, t);
  }

  // batched projection + big logits GEMM with fused softmax partials
  k_out    <<<dim3(E_ / 64, T_), 256, 0, stream>>>(hAll, WrB, br, outAll);
  k_logits2<<<dim3(MROWS / 128, NCB), 256, 0, stream>>>(outAll, embB, bd, part);
  k_tgt    <<<MROWS / 4, 256, 0, stream>>>(outAll, embB, bd, data, tgt);

  k_lse    <<<MROWS / 4, 256, 0, stream>>>(part, tgt, mask, rowNll);
  k_final2 <<<1, 256, 0, stream>>>(rowNll, (float*)d_out);
}